// Round 1
// baseline (4755.798 us; speedup 1.0000x reference)
//
#include <hip/hip_runtime.h>
#include <hip/hip_bf16.h>

constexpr int L = 6, B = 16, S = 512, D = 512, SD = 128, E = 1536;

// ---------------- mask layout detection ----------------
// If src_mask was pushed as 1-byte bools, some byte at offset %4 != 0 is 1.
// If pushed as int32 (values 0/1), all bytes at offset %4 != 0 are 0.
__global__ void detect_mask_kernel(const unsigned char* __restrict__ m, int* flag) {
    if (threadIdx.x == 0) *flag = 0;
    __syncthreads();
    int any = 0;
    for (int i = threadIdx.x; i < B * S; i += blockDim.x)
        if ((i & 3) != 0 && m[i] != 0) any = 1;
    if (any) atomicOr(flag, 1);
}

// ---------------- embedding + positional encoding ----------------
__global__ void embed_kernel(const int* __restrict__ tok, const float* __restrict__ embed,
                             float* __restrict__ x) {
    int idx = blockIdx.x * blockDim.x + threadIdx.x;      // over B*S*D
    int d = idx & (D - 1);
    int bs = idx >> 9;                                    // D = 512 = 2^9
    int s = bs & (S - 1);
    float e = embed[(size_t)tok[bs] * D + d] * 22.62741699796952f;  // sqrt(512)
    float expo = (float)(d >> 1) * (1.0f / 256.0f);       // 2*floor(d/2)/D
    float ang = (float)s * expf(expo * -9.210340371976184f);  // s * 10000^-expo
    float pe = (d & 1) ? cosf(ang) : sinf(ang);
    x[idx] = e + pe;
}

// ---------------- layernorm: one wave per row of D=512 ----------------
__global__ __launch_bounds__(64) void ln_kernel(const float* __restrict__ x,
                                                const float* __restrict__ g,
                                                const float* __restrict__ b,
                                                float* __restrict__ y) {
    int row = blockIdx.x;
    int lane = threadIdx.x;
    const float* xr = x + (size_t)row * D;
    float4 v0 = *(const float4*)(xr + lane * 4);
    float4 v1 = *(const float4*)(xr + 256 + lane * 4);
    float sum = v0.x + v0.y + v0.z + v0.w + v1.x + v1.y + v1.z + v1.w;
#pragma unroll
    for (int o = 1; o < 64; o <<= 1) sum += __shfl_xor(sum, o);
    float m = sum * (1.0f / D);
    float d0 = v0.x - m, d1 = v0.y - m, d2 = v0.z - m, d3 = v0.w - m;
    float e0 = v1.x - m, e1 = v1.y - m, e2 = v1.z - m, e3 = v1.w - m;
    float sq = d0 * d0 + d1 * d1 + d2 * d2 + d3 * d3 + e0 * e0 + e1 * e1 + e2 * e2 + e3 * e3;
#pragma unroll
    for (int o = 1; o < 64; o <<= 1) sq += __shfl_xor(sq, o);
    float inv = rsqrtf(sq * (1.0f / D) + 1e-5f);
    float* yr = y + (size_t)row * D;
    int c0 = lane * 4, c1 = 256 + lane * 4;
    float4 g0 = *(const float4*)(g + c0), g1 = *(const float4*)(g + c1);
    float4 b0 = *(const float4*)(b + c0), b1 = *(const float4*)(b + c1);
    float4 o0, o1;
    o0.x = d0 * inv * g0.x + b0.x;
    o0.y = d1 * inv * g0.y + b0.y;
    o0.z = d2 * inv * g0.z + b0.z;
    o0.w = d3 * inv * g0.w + b0.w;
    o1.x = e0 * inv * g1.x + b1.x;
    o1.y = e1 * inv * g1.y + b1.y;
    o1.z = e2 * inv * g1.z + b1.z;
    o1.w = e3 * inv * g1.w + b1.w;
    *(float4*)(yr + c0) = o0;
    *(float4*)(yr + c1) = o1;
}

// ---------------- generic fp32 tiled GEMM: C = A@W + bias (+ addend) ----------------
// A: M x K row-major, W: K x N row-major. M,N %64==0, K %16==0.
__global__ __launch_bounds__(256) void gemm_kernel(const float* __restrict__ A,
                                                   const float* __restrict__ W,
                                                   const float* __restrict__ bias,
                                                   const float* __restrict__ addend,
                                                   float* __restrict__ C,
                                                   int M, int N, int K) {
    __shared__ float As[16][68];
    __shared__ float Ws[16][68];
    int tid = threadIdx.x;
    int tx = tid & 15, ty = tid >> 4;
    int row0 = blockIdx.x * 64, col0 = blockIdx.y * 64;
    int lr = tid >> 2, lk = (tid & 3) * 4;
    int wk = tid >> 4, wc = (tid & 15) * 4;
    float acc[4][4] = {};
    for (int k0 = 0; k0 < K; k0 += 16) {
        float4 av = *(const float4*)(A + (size_t)(row0 + lr) * K + k0 + lk);
        float4 wv = *(const float4*)(W + (size_t)(k0 + wk) * N + col0 + wc);
        As[lk + 0][lr] = av.x; As[lk + 1][lr] = av.y; As[lk + 2][lr] = av.z; As[lk + 3][lr] = av.w;
        *(float4*)(&Ws[wk][wc]) = wv;
        __syncthreads();
#pragma unroll
        for (int t = 0; t < 16; ++t) {
            float ar[4], wr[4];
#pragma unroll
            for (int i = 0; i < 4; ++i) ar[i] = As[t][ty * 4 + i];
#pragma unroll
            for (int j = 0; j < 4; ++j) wr[j] = Ws[t][tx * 4 + j];
#pragma unroll
            for (int i = 0; i < 4; ++i)
#pragma unroll
                for (int j = 0; j < 4; ++j) acc[i][j] += ar[i] * wr[j];
        }
        __syncthreads();
    }
#pragma unroll
    for (int i = 0; i < 4; ++i) {
        int r = row0 + ty * 4 + i;
#pragma unroll
        for (int j = 0; j < 4; ++j) {
            int c = col0 + tx * 4 + j;
            float val = acc[i][j] + bias[c];
            if (addend) val += addend[(size_t)r * N + c];
            C[(size_t)r * N + c] = val;
        }
    }
}

// ---------------- q,k elementwise: q = z*gq+bq, k = z*gk+bk ----------------
__global__ void qk_kernel(const float* __restrict__ z, const float* __restrict__ gq,
                          const float* __restrict__ bq, const float* __restrict__ gk,
                          const float* __restrict__ bk, float* __restrict__ q,
                          float* __restrict__ k) {
    int idx = blockIdx.x * blockDim.x + threadIdx.x;   // over B*S*SD
    int sc = idx & (S * SD - 1);                       // S*SD = 65536 pow2
    float zv = z[idx];
    q[idx] = fmaf(zv, gq[sc], bq[sc]);
    k[idx] = fmaf(zv, gk[sc], bk[sc]);
}

// ---------------- scores: a[b,s,t] = relu(q·k)^2, masked on key t ----------------
__global__ __launch_bounds__(256) void score_kernel(const float* __restrict__ q,
                                                    const float* __restrict__ kmat,
                                                    const unsigned char* __restrict__ maskb,
                                                    const int* __restrict__ flagp,
                                                    float* __restrict__ a) {
    int bi = blockIdx.z;
    const float* Q = q + (size_t)bi * S * SD;
    const float* Km = kmat + (size_t)bi * S * SD;
    float* A = a + (size_t)bi * S * S;
    __shared__ float Qs[16][68];
    __shared__ float Ks[16][68];
    int tid = threadIdx.x;
    int tx = tid & 15, ty = tid >> 4;
    int row0 = blockIdx.x * 64, col0 = blockIdx.y * 64;
    int lr = tid >> 2, lk = (tid & 3) * 4;
    float acc[4][4] = {};
    for (int k0 = 0; k0 < SD; k0 += 16) {
        float4 qv = *(const float4*)(Q + (size_t)(row0 + lr) * SD + k0 + lk);
        float4 kv = *(const float4*)(Km + (size_t)(col0 + lr) * SD + k0 + lk);
        Qs[lk + 0][lr] = qv.x; Qs[lk + 1][lr] = qv.y; Qs[lk + 2][lr] = qv.z; Qs[lk + 3][lr] = qv.w;
        Ks[lk + 0][lr] = kv.x; Ks[lk + 1][lr] = kv.y; Ks[lk + 2][lr] = kv.z; Ks[lk + 3][lr] = kv.w;
        __syncthreads();
#pragma unroll
        for (int t = 0; t < 16; ++t) {
            float ar[4], kr[4];
#pragma unroll
            for (int i = 0; i < 4; ++i) ar[i] = Qs[t][ty * 4 + i];
#pragma unroll
            for (int j = 0; j < 4; ++j) kr[j] = Ks[t][tx * 4 + j];
#pragma unroll
            for (int i = 0; i < 4; ++i)
#pragma unroll
                for (int j = 0; j < 4; ++j) acc[i][j] += ar[i] * kr[j];
        }
        __syncthreads();
    }
    int flag = *flagp;
#pragma unroll
    for (int i = 0; i < 4; ++i) {
        int r = row0 + ty * 4 + i;
#pragma unroll
        for (int j = 0; j < 4; ++j) {
            int c = col0 + tx * 4 + j;
            float vv = fmaxf(acc[i][j], 0.0f);
            vv *= vv;
            int mv = flag ? (int)maskb[bi * S + c] : ((const int*)maskb)[bi * S + c];
            A[(size_t)r * S + c] = mv ? 0.0f : vv;
        }
    }
}

// ---------------- o = u * (a @ v), in-place into u ----------------
__global__ __launch_bounds__(256) void av_kernel(const float* __restrict__ a,
                                                 const float* __restrict__ v,
                                                 float* __restrict__ uo) {
    int bi = blockIdx.z;
    const float* A = a + (size_t)bi * S * S;
    const float* W = v + (size_t)bi * S * E;
    float* UO = uo + (size_t)bi * S * E;
    __shared__ float As[16][68];
    __shared__ float Ws[16][68];
    int tid = threadIdx.x;
    int tx = tid & 15, ty = tid >> 4;
    int row0 = blockIdx.x * 64, col0 = blockIdx.y * 64;
    int lr = tid >> 2, lk = (tid & 3) * 4;
    int wk = tid >> 4, wc = (tid & 15) * 4;
    float acc[4][4] = {};
    for (int k0 = 0; k0 < S; k0 += 16) {
        float4 av = *(const float4*)(A + (size_t)(row0 + lr) * S + k0 + lk);
        float4 wv = *(const float4*)(W + (size_t)(k0 + wk) * E + col0 + wc);
        As[lk + 0][lr] = av.x; As[lk + 1][lr] = av.y; As[lk + 2][lr] = av.z; As[lk + 3][lr] = av.w;
        *(float4*)(&Ws[wk][wc]) = wv;
        __syncthreads();
#pragma unroll
        for (int t = 0; t < 16; ++t) {
            float ar[4], wr[4];
#pragma unroll
            for (int i = 0; i < 4; ++i) ar[i] = As[t][ty * 4 + i];
#pragma unroll
            for (int j = 0; j < 4; ++j) wr[j] = Ws[t][tx * 4 + j];
#pragma unroll
            for (int i = 0; i < 4; ++i)
#pragma unroll
                for (int j = 0; j < 4; ++j) acc[i][j] += ar[i] * wr[j];
        }
        __syncthreads();
    }
#pragma unroll
    for (int i = 0; i < 4; ++i) {
        int r = row0 + ty * 4 + i;
#pragma unroll
        for (int j = 0; j < 4; ++j) {
            int c = col0 + tx * 4 + j;
            size_t off = (size_t)r * E + c;
            UO[off] = UO[off] * acc[i][j];
        }
    }
}

extern "C" void kernel_launch(void* const* d_in, const int* in_sizes, int n_in,
                              void* d_out, int out_size, void* d_ws, size_t ws_size,
                              hipStream_t stream) {
    const int* tok = (const int*)d_in[0];
    const unsigned char* mask = (const unsigned char*)d_in[1];
    const float* embed = (const float*)d_in[2];
    const float* ln_g = (const float*)d_in[3];
    const float* ln_b = (const float*)d_in[4];
    const float* Wz = (const float*)d_in[5];
    const float* bz = (const float*)d_in[6];
    const float* gq = (const float*)d_in[7];
    const float* bq = (const float*)d_in[8];
    const float* gk = (const float*)d_in[9];
    const float* bk = (const float*)d_in[10];
    const float* Wu = (const float*)d_in[11];
    const float* bu = (const float*)d_in[12];
    const float* Wv = (const float*)d_in[13];
    const float* bv = (const float*)d_in[14];
    const float* Wo = (const float*)d_in[15];
    const float* bo = (const float*)d_in[16];
    const float* fin_g = (const float*)d_in[17];
    const float* fin_b = (const float*)d_in[18];

    char* wsb = (char*)d_ws;
    size_t off = 0;
    auto alloc = [&](size_t nbytes) {
        void* p = wsb + off;
        off = (off + nbytes + 255) & ~(size_t)255;
        return p;
    };
    int* flag = (int*)alloc(256);
    float* x = (float*)alloc((size_t)B * S * D * 4);
    float* xn = (float*)alloc((size_t)B * S * D * 4);   // reused as 'a' (same size: D==S)
    float* z = (float*)alloc((size_t)B * S * SD * 4);
    float* q = (float*)alloc((size_t)B * S * SD * 4);
    float* kb = (float*)alloc((size_t)B * S * SD * 4);
    float* u = (float*)alloc((size_t)B * S * E * 4);    // reused as 'o' (in-place multiply)
    float* v = (float*)alloc((size_t)B * S * E * 4);
    float* a = xn;

    detect_mask_kernel<<<1, 256, 0, stream>>>(mask, flag);
    embed_kernel<<<(B * S * D) / 256, 256, 0, stream>>>(tok, embed, x);

    for (int l = 0; l < L; ++l) {
        ln_kernel<<<B * S, 64, 0, stream>>>(x, ln_g + l * D, ln_b + l * D, xn);
        gemm_kernel<<<dim3(B * S / 64, E / 64), 256, 0, stream>>>(
            xn, Wu + (size_t)l * D * E, bu + l * E, nullptr, u, B * S, E, D);
        gemm_kernel<<<dim3(B * S / 64, E / 64), 256, 0, stream>>>(
            xn, Wv + (size_t)l * D * E, bv + l * E, nullptr, v, B * S, E, D);
        gemm_kernel<<<dim3(B * S / 64, SD / 64), 256, 0, stream>>>(
            xn, Wz + (size_t)l * D * SD, bz + l * SD, nullptr, z, B * S, SD, D);
        qk_kernel<<<(B * S * SD) / 256, 256, 0, stream>>>(
            z, gq + (size_t)l * S * SD, bq + (size_t)l * S * SD,
            gk + (size_t)l * S * SD, bk + (size_t)l * S * SD, q, kb);
        score_kernel<<<dim3(S / 64, S / 64, B), 256, 0, stream>>>(q, kb, mask, flag, a);
        av_kernel<<<dim3(S / 64, E / 64, B), 256, 0, stream>>>(a, v, u);
        gemm_kernel<<<dim3(B * S / 64, D / 64), 256, 0, stream>>>(
            u, Wo + (size_t)l * E * D, bo + l * D, x, x, B * S, D, E);
    }
    ln_kernel<<<B * S, 64, 0, stream>>>(x, fin_g, fin_b, (float*)d_out);
}

// Round 2
// 916.003 us; speedup vs baseline: 5.1919x; 5.1919x over previous
//
#include <hip/hip_runtime.h>
#include <hip/hip_bf16.h>
#include <stdint.h>

constexpr int L = 6, B = 16, S = 512, D = 512, SD = 128, E = 1536;

using bf16x8 = __attribute__((ext_vector_type(8))) short;
using f32x4  = __attribute__((ext_vector_type(4))) float;

typedef __attribute__((address_space(1))) void gvoid;
typedef __attribute__((address_space(3))) void lvoid;

__device__ __forceinline__ unsigned short f2bf(float f) {
    __hip_bfloat16 h = __float2bfloat16(f);
    return __builtin_bit_cast(unsigned short, h);
}
__device__ __forceinline__ float bf2f(unsigned short u) {
    unsigned int v = ((unsigned int)u) << 16;
    return __builtin_bit_cast(float, v);
}
__device__ __forceinline__ void gload16(const void* g, void* l) {
    __builtin_amdgcn_global_load_lds((gvoid*)g, (lvoid*)l, 16, 0, 0);
}

// ---------------- mask layout detection ----------------
__global__ void detect_mask_kernel(const unsigned char* __restrict__ m, int* flag) {
    if (threadIdx.x == 0) *flag = 0;
    __syncthreads();
    int any = 0;
    for (int i = threadIdx.x; i < B * S; i += blockDim.x)
        if ((i & 3) != 0 && m[i] != 0) any = 1;
    if (any) atomicOr(flag, 1);
}

// ---------------- embedding + positional encoding ----------------
__global__ void embed_kernel(const int* __restrict__ tok, const float* __restrict__ embed,
                             float* __restrict__ x) {
    int idx = blockIdx.x * blockDim.x + threadIdx.x;      // over B*S*D
    int d = idx & (D - 1);
    int bs = idx >> 9;                                    // D = 512 = 2^9
    int s = bs & (S - 1);
    float e = embed[(size_t)tok[bs] * D + d] * 22.62741699796952f;  // sqrt(512)
    float expo = (float)(d >> 1) * (1.0f / 256.0f);
    float ang = (float)s * expf(expo * -9.210340371976184f);
    float pe = (d & 1) ? cosf(ang) : sinf(ang);
    x[idx] = e + pe;
}

// ---------------- weight transpose + cast: W (K x N f32) -> Wt (N x K bf16) ----------
__global__ __launch_bounds__(256) void tcast_kernel(const float* __restrict__ W,
                                                    unsigned short* __restrict__ Wt,
                                                    int K, int N) {
    __shared__ float t[32][33];
    W  += (size_t)blockIdx.z * K * N;
    Wt += (size_t)blockIdx.z * K * N;
    int k0 = blockIdx.x * 32, n0 = blockIdx.y * 32;
    int tx = threadIdx.x, ty = threadIdx.y;               // 32 x 8
#pragma unroll
    for (int i = 0; i < 4; ++i)
        t[ty + i * 8][tx] = W[(size_t)(k0 + ty + i * 8) * N + n0 + tx];
    __syncthreads();
#pragma unroll
    for (int i = 0; i < 4; ++i)
        Wt[(size_t)(n0 + ty + i * 8) * K + k0 + tx] = f2bf(t[tx][ty + i * 8]);
}

// ---------------- layernorm: one wave per row of D=512 ----------------
template <bool BF>
__global__ __launch_bounds__(64) void ln_kernel(const float* __restrict__ x,
                                                const float* __restrict__ g,
                                                const float* __restrict__ b,
                                                void* __restrict__ yp) {
    int row = blockIdx.x;
    int lane = threadIdx.x;
    const float* xr = x + (size_t)row * D;
    float4 v0 = *(const float4*)(xr + lane * 4);
    float4 v1 = *(const float4*)(xr + 256 + lane * 4);
    float sum = v0.x + v0.y + v0.z + v0.w + v1.x + v1.y + v1.z + v1.w;
#pragma unroll
    for (int o = 1; o < 64; o <<= 1) sum += __shfl_xor(sum, o);
    float m = sum * (1.0f / D);
    float d0 = v0.x - m, d1 = v0.y - m, d2 = v0.z - m, d3 = v0.w - m;
    float e0 = v1.x - m, e1 = v1.y - m, e2 = v1.z - m, e3 = v1.w - m;
    float sq = d0 * d0 + d1 * d1 + d2 * d2 + d3 * d3 + e0 * e0 + e1 * e1 + e2 * e2 + e3 * e3;
#pragma unroll
    for (int o = 1; o < 64; o <<= 1) sq += __shfl_xor(sq, o);
    float inv = rsqrtf(sq * (1.0f / D) + 1e-5f);
    int c0 = lane * 4, c1 = 256 + lane * 4;
    float4 g0 = *(const float4*)(g + c0), g1 = *(const float4*)(g + c1);
    float4 b0 = *(const float4*)(b + c0), b1 = *(const float4*)(b + c1);
    float o0 = d0 * inv * g0.x + b0.x, o1 = d1 * inv * g0.y + b0.y;
    float o2 = d2 * inv * g0.z + b0.z, o3 = d3 * inv * g0.w + b0.w;
    float o4 = e0 * inv * g1.x + b1.x, o5 = e1 * inv * g1.y + b1.y;
    float o6 = e2 * inv * g1.z + b1.z, o7 = e3 * inv * g1.w + b1.w;
    if constexpr (BF) {
        unsigned short* yr = (unsigned short*)yp + (size_t)row * D;
        ushort4 p0 = {f2bf(o0), f2bf(o1), f2bf(o2), f2bf(o3)};
        ushort4 p1 = {f2bf(o4), f2bf(o5), f2bf(o6), f2bf(o7)};
        *(ushort4*)(yr + c0) = p0;
        *(ushort4*)(yr + c1) = p1;
    } else {
        float* yr = (float*)yp + (size_t)row * D;
        float4 p0 = {o0, o1, o2, o3}, p1 = {o4, o5, o6, o7};
        *(float4*)(yr + c0) = p0;
        *(float4*)(yr + c1) = p1;
    }
}

// ---------------- q,k elementwise: bf16 out ----------------
__global__ void qk_kernel(const float* __restrict__ z, const float* __restrict__ gq,
                          const float* __restrict__ bq, const float* __restrict__ gk,
                          const float* __restrict__ bk, unsigned short* __restrict__ q,
                          unsigned short* __restrict__ k) {
    int idx = blockIdx.x * blockDim.x + threadIdx.x;   // over B*S*SD
    int sc = idx & (S * SD - 1);
    float zv = z[idx];
    q[idx] = f2bf(fmaf(zv, gq[sc], bq[sc]));
    k[idx] = f2bf(fmaf(zv, gk[sc], bk[sc]));
}

// ---------------- bf16 MFMA GEMM: C = A(MxK) @ Bt(NxK)^T, fused epilogues ----------
// BM=BN=128, BK=64, 256 threads = 4 waves (2x2), each wave 64x64 (4x4 frags 16x16).
// LDS tiles [128 rows][64 k] bf16, chunk-XOR swizzle: phys_chunk = log_chunk ^ (row&7).
// Staging via global_load_lds(16B) with pre-swizzled per-lane global source.
// EPI: 0 bias->bf16 | 1 bias->f32 | 2 bias->bf16 transposed batched (v^T) |
//      3 relu^2+mask->bf16 | 4 u*acc->bf16 | 5 bias+residual->f32
template <int EPI>
__global__ __launch_bounds__(256) void mgemm(const unsigned short* __restrict__ A,
                                             const unsigned short* __restrict__ Bt,
                                             const float* __restrict__ bias,
                                             const void* __restrict__ aux,
                                             const int* __restrict__ flagp,
                                             void* __restrict__ Cp,
                                             int N, int K,
                                             long sA, long sB, long sC, long sAux) {
    __shared__ short lsA[128 * 64];
    __shared__ short lsB[128 * 64];
    const int tid = threadIdx.x;
    const int lane = tid & 63, wv = tid >> 6;
    const int wm = wv >> 1, wn = wv & 1;
    const int row0 = blockIdx.x * 128, col0 = blockIdx.y * 128;
    const int bz = blockIdx.z;

    const unsigned short* Ab = A + (size_t)bz * sA + (size_t)row0 * K;
    const unsigned short* Bb = Bt + (size_t)bz * sB + (size_t)col0 * K;

    // staging addresses: wave wv covers 1KB segments [wv*4, wv*4+4) of each tile
    const unsigned short* ga[4];
    const unsigned short* gb[4];
    int lofs[4];
#pragma unroll
    for (int i = 0; i < 4; ++i) {
        int s = wv * 4 + i;
        int r = s * 8 + (lane >> 3);            // tile row this lane's 16B lands in
        int cl = (lane & 7) ^ (r & 7);          // logical chunk for physical slot
        ga[i] = Ab + (size_t)r * K + cl * 8;
        gb[i] = Bb + (size_t)r * K + cl * 8;
        lofs[i] = s * 512;                      // wave-uniform LDS base (short idx)
    }

    f32x4 acc[4][4] = {};
    const int nkt = K >> 6;
    for (int kt = 0; kt < nkt; ++kt) {
        if (kt) __syncthreads();
#pragma unroll
        for (int i = 0; i < 4; ++i) {
            gload16(ga[i] + kt * 64, (void*)&lsA[lofs[i]]);
            gload16(gb[i] + kt * 64, (void*)&lsB[lofs[i]]);
        }
        __syncthreads();
#pragma unroll
        for (int ks = 0; ks < 2; ++ks) {
            bf16x8 aF[4], bF[4];
#pragma unroll
            for (int f = 0; f < 4; ++f) {
                int ra = wm * 64 + f * 16 + (lane & 15);
                int ca = (ks * 4 + (lane >> 4)) ^ (ra & 7);
                aF[f] = *(const bf16x8*)&lsA[ra * 64 + ca * 8];
                int rb = wn * 64 + f * 16 + (lane & 15);
                int cb = (ks * 4 + (lane >> 4)) ^ (rb & 7);
                bF[f] = *(const bf16x8*)&lsB[rb * 64 + cb * 8];
            }
#pragma unroll
            for (int fi = 0; fi < 4; ++fi)
#pragma unroll
                for (int fj = 0; fj < 4; ++fj)
                    acc[fi][fj] = __builtin_amdgcn_mfma_f32_16x16x32_bf16(
                        aF[fi], bF[fj], acc[fi][fj], 0, 0, 0);
        }
    }

    // epilogue: C frag mapping col = lane&15, row = (lane>>4)*4 + reg
    const int lr4 = (lane >> 4) * 4;
    const int lc = lane & 15;
#pragma unroll
    for (int fi = 0; fi < 4; ++fi) {
        int rb = row0 + wm * 64 + fi * 16 + lr4;
#pragma unroll
        for (int fj = 0; fj < 4; ++fj) {
            int c = col0 + wn * 64 + fj * 16 + lc;
            f32x4 v = acc[fi][fj];
            if constexpr (EPI == 0) {
                float bv = bias[c];
                unsigned short* C = (unsigned short*)Cp;
#pragma unroll
                for (int g = 0; g < 4; ++g)
                    C[(size_t)(rb + g) * N + c] = f2bf(v[g] + bv);
            } else if constexpr (EPI == 1) {
                float bv = bias[c];
                float* C = (float*)Cp;
#pragma unroll
                for (int g = 0; g < 4; ++g)
                    C[(size_t)(rb + g) * N + c] = v[g] + bv;
            } else if constexpr (EPI == 2) {   // v^T: out[b][c][t], t contiguous
                float bv = bias[c];
                unsigned short* C = (unsigned short*)Cp;
                int b = rb >> 9, t0 = rb & 511;
                ushort4 o = {f2bf(v[0] + bv), f2bf(v[1] + bv),
                             f2bf(v[2] + bv), f2bf(v[3] + bv)};
                *(ushort4*)&C[((size_t)b * N + c) * 512 + t0] = o;
            } else if constexpr (EPI == 3) {   // relu^2 + key mask
                int mv = (*flagp) ? (int)((const unsigned char*)aux)[bz * sAux + c]
                                  : ((const int*)aux)[bz * sAux + c];
                unsigned short* C = (unsigned short*)Cp + (size_t)bz * sC;
#pragma unroll
                for (int g = 0; g < 4; ++g) {
                    float vv = fmaxf(v[g], 0.0f);
                    vv *= vv;
                    C[(size_t)(rb + g) * N + c] = mv ? (unsigned short)0 : f2bf(vv);
                }
            } else if constexpr (EPI == 4) {   // o = u * (a@v)
                const unsigned short* U = (const unsigned short*)aux + (size_t)bz * sAux;
                unsigned short* C = (unsigned short*)Cp + (size_t)bz * sC;
#pragma unroll
                for (int g = 0; g < 4; ++g) {
                    size_t off = (size_t)(rb + g) * N + c;
                    C[off] = f2bf(bf2f(U[off]) * v[g]);
                }
            } else {                           // EPI 5: bias + residual, f32 in-place
                float bv = bias[c];
                const float* X = (const float*)aux;
                float* C = (float*)Cp;
#pragma unroll
                for (int g = 0; g < 4; ++g) {
                    size_t off = (size_t)(rb + g) * N + c;
                    C[off] = v[g] + bv + X[off];
                }
            }
        }
    }
}

extern "C" void kernel_launch(void* const* d_in, const int* in_sizes, int n_in,
                              void* d_out, int out_size, void* d_ws, size_t ws_size,
                              hipStream_t stream) {
    const int* tok = (const int*)d_in[0];
    const unsigned char* mask = (const unsigned char*)d_in[1];
    const float* embed = (const float*)d_in[2];
    const float* ln_g = (const float*)d_in[3];
    const float* ln_b = (const float*)d_in[4];
    const float* Wz = (const float*)d_in[5];
    const float* bz = (const float*)d_in[6];
    const float* gq = (const float*)d_in[7];
    const float* bq = (const float*)d_in[8];
    const float* gk = (const float*)d_in[9];
    const float* bk = (const float*)d_in[10];
    const float* Wu = (const float*)d_in[11];
    const float* bu = (const float*)d_in[12];
    const float* Wv = (const float*)d_in[13];
    const float* bv = (const float*)d_in[14];
    const float* Wo = (const float*)d_in[15];
    const float* bo = (const float*)d_in[16];
    const float* fin_g = (const float*)d_in[17];
    const float* fin_b = (const float*)d_in[18];

    char* wsb = (char*)d_ws;
    size_t off = 0;
    auto alloc = [&](size_t nbytes) {
        void* p = wsb + off;
        off = (off + nbytes + 255) & ~(size_t)255;
        return p;
    };
    int* flag = (int*)alloc(256);
    float* x = (float*)alloc((size_t)B * S * D * 4);
    unsigned short* xn = (unsigned short*)alloc((size_t)B * S * D * 2);
    float* z = (float*)alloc((size_t)B * S * SD * 4);
    unsigned short* q = (unsigned short*)alloc((size_t)B * S * SD * 2);
    unsigned short* k = (unsigned short*)alloc((size_t)B * S * SD * 2);
    unsigned short* u = (unsigned short*)alloc((size_t)B * S * E * 2);
    unsigned short* vt = (unsigned short*)alloc((size_t)B * E * S * 2);
    unsigned short* o = (unsigned short*)alloc((size_t)B * S * E * 2);
    unsigned short* a = (unsigned short*)alloc((size_t)B * S * S * 2);
    unsigned short* Wut = (unsigned short*)alloc((size_t)L * E * D * 2);
    unsigned short* Wvt = (unsigned short*)alloc((size_t)L * E * D * 2);
    unsigned short* Wzt = (unsigned short*)alloc((size_t)L * SD * D * 2);
    unsigned short* Wot = (unsigned short*)alloc((size_t)L * D * E * 2);

    detect_mask_kernel<<<1, 256, 0, stream>>>(mask, flag);
    embed_kernel<<<(B * S * D) / 256, 256, 0, stream>>>(tok, embed, x);
    tcast_kernel<<<dim3(D / 32, E / 32, L), dim3(32, 8), 0, stream>>>(Wu, Wut, D, E);
    tcast_kernel<<<dim3(D / 32, E / 32, L), dim3(32, 8), 0, stream>>>(Wv, Wvt, D, E);
    tcast_kernel<<<dim3(D / 32, SD / 32, L), dim3(32, 8), 0, stream>>>(Wz, Wzt, D, SD);
    tcast_kernel<<<dim3(E / 32, D / 32, L), dim3(32, 8), 0, stream>>>(Wo, Wot, E, D);

    for (int l = 0; l < L; ++l) {
        ln_kernel<true><<<B * S, 64, 0, stream>>>(x, ln_g + l * D, ln_b + l * D, xn);
        mgemm<0><<<dim3(64, E / 128, 1), 256, 0, stream>>>(
            xn, Wut + (size_t)l * E * D, bu + l * E, nullptr, nullptr, u, E, D, 0, 0, 0, 0);
        mgemm<2><<<dim3(64, E / 128, 1), 256, 0, stream>>>(
            xn, Wvt + (size_t)l * E * D, bv + l * E, nullptr, nullptr, vt, E, D, 0, 0, 0, 0);
        mgemm<1><<<dim3(64, 1, 1), 256, 0, stream>>>(
            xn, Wzt + (size_t)l * SD * D, bz + l * SD, nullptr, nullptr, z, SD, D, 0, 0, 0, 0);
        qk_kernel<<<(B * S * SD) / 256, 256, 0, stream>>>(
            z, gq + (size_t)l * S * SD, bq + (size_t)l * S * SD,
            gk + (size_t)l * S * SD, bk + (size_t)l * S * SD, q, k);
        mgemm<3><<<dim3(4, 4, B), 256, 0, stream>>>(
            q, k, nullptr, mask, flag, a, S, SD,
            (long)S * SD, (long)S * SD, (long)S * S, S);
        mgemm<4><<<dim3(4, E / 128, B), 256, 0, stream>>>(
            a, vt, nullptr, u, nullptr, o, E, S,
            (long)S * S, (long)E * S, (long)S * E, (long)S * E);
        mgemm<5><<<dim3(64, D / 128, 1), 256, 0, stream>>>(
            o, Wot + (size_t)l * D * E, bo + l * D, x, nullptr, x, D, E, 0, 0, 0, 0);
    }
    ln_kernel<false><<<B * S, 64, 0, stream>>>(x, fin_g, fin_b, (float*)d_out);
}

// Round 3
// 813.439 us; speedup vs baseline: 5.8465x; 1.1261x over previous
//
#include <hip/hip_runtime.h>
#include <hip/hip_bf16.h>
#include <stdint.h>

constexpr int L = 6, B = 16, S = 512, D = 512, SD = 128, E = 1536;

using bf16x8 = __attribute__((ext_vector_type(8))) short;
using f32x4  = __attribute__((ext_vector_type(4))) float;

typedef __attribute__((address_space(1))) void gvoid;
typedef __attribute__((address_space(3))) void lvoid;

__device__ __forceinline__ unsigned short f2bf(float f) {
    __hip_bfloat16 h = __float2bfloat16(f);
    return __builtin_bit_cast(unsigned short, h);
}
__device__ __forceinline__ float bf2f(unsigned short u) {
    unsigned int v = ((unsigned int)u) << 16;
    return __builtin_bit_cast(float, v);
}
__device__ __forceinline__ void gload16(const void* g, void* l) {
    __builtin_amdgcn_global_load_lds((gvoid*)g, (lvoid*)l, 16, 0, 0);
}

// ---------------- mask layout detection ----------------
__global__ void detect_mask_kernel(const unsigned char* __restrict__ m, int* flag) {
    if (threadIdx.x == 0) *flag = 0;
    __syncthreads();
    int any = 0;
    for (int i = threadIdx.x; i < B * S; i += blockDim.x)
        if ((i & 3) != 0 && m[i] != 0) any = 1;
    if (any) atomicOr(flag, 1);
}

// ---------------- embedding + positional encoding ----------------
__global__ void embed_kernel(const int* __restrict__ tok, const float* __restrict__ embed,
                             float* __restrict__ x) {
    int idx = blockIdx.x * blockDim.x + threadIdx.x;      // over B*S*D
    int d = idx & (D - 1);
    int bs = idx >> 9;                                    // D = 512 = 2^9
    int s = bs & (S - 1);
    float e = embed[(size_t)tok[bs] * D + d] * 22.62741699796952f;  // sqrt(512)
    float expo = (float)(d >> 1) * (1.0f / 256.0f);
    float ang = (float)s * expf(expo * -9.210340371976184f);
    float pe = (d & 1) ? cosf(ang) : sinf(ang);
    x[idx] = e + pe;
}

// ---- weight transpose + cast: W (K x N f32) -> Wt (N x K bf16), per-layer out stride ----
__global__ __launch_bounds__(256) void tcast_kernel(const float* __restrict__ W,
                                                    unsigned short* __restrict__ Wt,
                                                    int K, int N, long ostride) {
    __shared__ float t[32][33];
    W  += (size_t)blockIdx.z * K * N;
    Wt += (size_t)blockIdx.z * ostride;
    int k0 = blockIdx.x * 32, n0 = blockIdx.y * 32;
    int tx = threadIdx.x, ty = threadIdx.y;               // 32 x 8
#pragma unroll
    for (int i = 0; i < 4; ++i)
        t[ty + i * 8][tx] = W[(size_t)(k0 + ty + i * 8) * N + n0 + tx];
    __syncthreads();
#pragma unroll
    for (int i = 0; i < 4; ++i)
        Wt[(size_t)(n0 + ty + i * 8) * K + k0 + tx] = f2bf(t[tx][ty + i * 8]);
}

// ---------------- layernorm: one wave per row of D=512 ----------------
template <bool BF>
__global__ __launch_bounds__(64) void ln_kernel(const float* __restrict__ x,
                                                const float* __restrict__ g,
                                                const float* __restrict__ b,
                                                void* __restrict__ yp) {
    int row = blockIdx.x;
    int lane = threadIdx.x;
    const float* xr = x + (size_t)row * D;
    float4 v0 = *(const float4*)(xr + lane * 4);
    float4 v1 = *(const float4*)(xr + 256 + lane * 4);
    float sum = v0.x + v0.y + v0.z + v0.w + v1.x + v1.y + v1.z + v1.w;
#pragma unroll
    for (int o = 1; o < 64; o <<= 1) sum += __shfl_xor(sum, o);
    float m = sum * (1.0f / D);
    float d0 = v0.x - m, d1 = v0.y - m, d2 = v0.z - m, d3 = v0.w - m;
    float e0 = v1.x - m, e1 = v1.y - m, e2 = v1.z - m, e3 = v1.w - m;
    float sq = d0 * d0 + d1 * d1 + d2 * d2 + d3 * d3 + e0 * e0 + e1 * e1 + e2 * e2 + e3 * e3;
#pragma unroll
    for (int o = 1; o < 64; o <<= 1) sq += __shfl_xor(sq, o);
    float inv = rsqrtf(sq * (1.0f / D) + 1e-5f);
    int c0 = lane * 4, c1 = 256 + lane * 4;
    float4 g0 = *(const float4*)(g + c0), g1 = *(const float4*)(g + c1);
    float4 b0 = *(const float4*)(b + c0), b1 = *(const float4*)(b + c1);
    float o0 = d0 * inv * g0.x + b0.x, o1 = d1 * inv * g0.y + b0.y;
    float o2 = d2 * inv * g0.z + b0.z, o3 = d3 * inv * g0.w + b0.w;
    float o4 = e0 * inv * g1.x + b1.x, o5 = e1 * inv * g1.y + b1.y;
    float o6 = e2 * inv * g1.z + b1.z, o7 = e3 * inv * g1.w + b1.w;
    if constexpr (BF) {
        unsigned short* yr = (unsigned short*)yp + (size_t)row * D;
        ushort4 p0 = {f2bf(o0), f2bf(o1), f2bf(o2), f2bf(o3)};
        ushort4 p1 = {f2bf(o4), f2bf(o5), f2bf(o6), f2bf(o7)};
        *(ushort4*)(yr + c0) = p0;
        *(ushort4*)(yr + c1) = p1;
    } else {
        float* yr = (float*)yp + (size_t)row * D;
        float4 p0 = {o0, o1, o2, o3}, p1 = {o4, o5, o6, o7};
        *(float4*)(yr + c0) = p0;
        *(float4*)(yr + c1) = p1;
    }
}

// ---------------- q,k elementwise: bf16 out ----------------
__global__ void qk_kernel(const float* __restrict__ z, const float* __restrict__ gq,
                          const float* __restrict__ bq, const float* __restrict__ gk,
                          const float* __restrict__ bk, unsigned short* __restrict__ q,
                          unsigned short* __restrict__ k) {
    int idx = blockIdx.x * blockDim.x + threadIdx.x;   // over B*S*SD
    int sc = idx & (S * SD - 1);
    float zv = z[idx];
    q[idx] = f2bf(fmaf(zv, gq[sc], bq[sc]));
    k[idx] = f2bf(fmaf(zv, gk[sc], bk[sc]));
}

// ---------------- MFMA GEMM core: tile BM x BN, BK=64, 4 waves (2x2) ----------------
// LDS tiles [rows][64] bf16, chunk-XOR swizzle: phys_chunk = log_chunk ^ (row&7).
// Staging via global_load_lds(16B), pre-swizzled per-lane global source.
template <int BM, int BN>
__device__ __forceinline__ void gemm_core(const unsigned short* __restrict__ Ab,
                                          const unsigned short* __restrict__ Bb,
                                          int K, short* lsA, short* lsB,
                                          f32x4 (&acc)[BM / 32][BN / 32],
                                          int lane, int wv) {
    constexpr int NA = BM / 32, NB = BN / 32;   // staged 1KB segments per wave
    constexpr int FM = BM / 32, FN = BN / 32;   // 16x16 frags per wave
    constexpr int WTM = BM / 2, WTN = BN / 2;   // wave tile
    const int wm = wv >> 1, wn = wv & 1;
    const unsigned short* ga[NA]; int lofsA[NA];
    const unsigned short* gb[NB]; int lofsB[NB];
#pragma unroll
    for (int i = 0; i < NA; ++i) {
        int s = wv * NA + i;
        int r = s * 8 + (lane >> 3);
        int cl = (lane & 7) ^ (r & 7);
        ga[i] = Ab + (size_t)r * K + cl * 8;
        lofsA[i] = s * 512;
    }
#pragma unroll
    for (int i = 0; i < NB; ++i) {
        int s = wv * NB + i;
        int r = s * 8 + (lane >> 3);
        int cl = (lane & 7) ^ (r & 7);
        gb[i] = Bb + (size_t)r * K + cl * 8;
        lofsB[i] = s * 512;
    }
    const int nkt = K >> 6;
    for (int kt = 0; kt < nkt; ++kt) {
        if (kt) __syncthreads();
#pragma unroll
        for (int i = 0; i < NA; ++i) gload16(ga[i] + kt * 64, (void*)&lsA[lofsA[i]]);
#pragma unroll
        for (int i = 0; i < NB; ++i) gload16(gb[i] + kt * 64, (void*)&lsB[lofsB[i]]);
        __syncthreads();
#pragma unroll
        for (int ks = 0; ks < 2; ++ks) {
            bf16x8 aF[FM], bF[FN];
#pragma unroll
            for (int f = 0; f < FM; ++f) {
                int ra = wm * WTM + f * 16 + (lane & 15);
                int ca = (ks * 4 + (lane >> 4)) ^ (ra & 7);
                aF[f] = *(const bf16x8*)&lsA[ra * 64 + ca * 8];
            }
#pragma unroll
            for (int f = 0; f < FN; ++f) {
                int rb = wn * WTN + f * 16 + (lane & 15);
                int cb = (ks * 4 + (lane >> 4)) ^ (rb & 7);
                bF[f] = *(const bf16x8*)&lsB[rb * 64 + cb * 8];
            }
#pragma unroll
            for (int fi = 0; fi < FM; ++fi)
#pragma unroll
                for (int fj = 0; fj < FN; ++fj)
                    acc[fi][fj] = __builtin_amdgcn_mfma_f32_16x16x32_bf16(
                        aF[fi], bF[fj], acc[fi][fj], 0, 0, 0);
        }
    }
}

// EPI: 3 relu^2+mask->bf16 | 4 u*acc->bf16 | 5 bias+residual->f32
template <int EPI, int BM, int BN>
__global__ __launch_bounds__(256) void mgemm(const unsigned short* __restrict__ A,
                                             const unsigned short* __restrict__ Bt,
                                             const float* __restrict__ bias,
                                             const void* __restrict__ aux,
                                             const int* __restrict__ flagp,
                                             void* __restrict__ Cp,
                                             int N, int K,
                                             long sA, long sB, long sC, long sAux) {
    __shared__ short lsA[BM * 64];
    __shared__ short lsB[BN * 64];
    constexpr int FM = BM / 32, FN = BN / 32;
    const int tid = threadIdx.x;
    const int lane = tid & 63, wv = tid >> 6;
    const int wm = wv >> 1, wn = wv & 1;
    const int row0 = blockIdx.x * BM, col0 = blockIdx.y * BN;
    const int bz = blockIdx.z;

    const unsigned short* Ab = A + (size_t)bz * sA + (size_t)row0 * K;
    const unsigned short* Bb = Bt + (size_t)bz * sB + (size_t)col0 * K;

    f32x4 acc[FM][FN] = {};
    gemm_core<BM, BN>(Ab, Bb, K, lsA, lsB, acc, lane, wv);

    const int lr4 = (lane >> 4) * 4;
    const int lc = lane & 15;
#pragma unroll
    for (int fi = 0; fi < FM; ++fi) {
        int rb = row0 + wm * (BM / 2) + fi * 16 + lr4;
#pragma unroll
        for (int fj = 0; fj < FN; ++fj) {
            int c = col0 + wn * (BN / 2) + fj * 16 + lc;
            f32x4 v = acc[fi][fj];
            if constexpr (EPI == 3) {   // relu^2 + key mask
                int mv = (*flagp) ? (int)((const unsigned char*)aux)[bz * sAux + c]
                                  : ((const int*)aux)[bz * sAux + c];
                unsigned short* C = (unsigned short*)Cp + (size_t)bz * sC;
#pragma unroll
                for (int g = 0; g < 4; ++g) {
                    float vv = fmaxf(v[g], 0.0f);
                    vv *= vv;
                    C[(size_t)(rb + g) * N + c] = mv ? (unsigned short)0 : f2bf(vv);
                }
            } else if constexpr (EPI == 4) {   // o = u * (a@v)
                const unsigned short* U = (const unsigned short*)aux + (size_t)bz * sAux;
                unsigned short* C = (unsigned short*)Cp + (size_t)bz * sC;
#pragma unroll
                for (int g = 0; g < 4; ++g) {
                    size_t off = (size_t)(rb + g) * N + c;
                    C[off] = f2bf(bf2f(U[off]) * v[g]);
                }
            } else {                           // EPI 5: bias + residual, f32 in-place
                float bv = bias[c];
                const float* X = (const float*)aux;
                float* C = (float*)Cp;
#pragma unroll
                for (int g = 0; g < 4; ++g) {
                    size_t off = (size_t)(rb + g) * N + c;
                    C[off] = v[g] + bv + X[off];
                }
            }
        }
    }
}

// ---------------- fused u|v|z GEMM: xn(8192x512) @ Wuvzt(3200x512)^T --------------
// col region: [0,1536) -> u bf16; [1536,3072) -> v^T bf16 batched; [3072,3200) -> z f32
__global__ __launch_bounds__(256) void uvz_gemm(const unsigned short* __restrict__ xn,
                                                const unsigned short* __restrict__ Wuvzt,
                                                const float* __restrict__ bu,
                                                const float* __restrict__ bvp,
                                                const float* __restrict__ bzp,
                                                unsigned short* __restrict__ u,
                                                unsigned short* __restrict__ vt,
                                                float* __restrict__ z) {
    __shared__ short lsA[128 * 64];
    __shared__ short lsB[128 * 64];
    const int tid = threadIdx.x;
    const int lane = tid & 63, wv = tid >> 6;
    const int wm = wv >> 1, wn = wv & 1;
    const int row0 = blockIdx.x * 128, col0 = blockIdx.y * 128;

    const unsigned short* Ab = xn + (size_t)row0 * D;
    const unsigned short* Bb = Wuvzt + (size_t)col0 * D;

    f32x4 acc[4][4] = {};
    gemm_core<128, 128>(Ab, Bb, D, lsA, lsB, acc, lane, wv);

    const int lr4 = (lane >> 4) * 4;
    const int lc = lane & 15;
#pragma unroll
    for (int fi = 0; fi < 4; ++fi) {
        int rb = row0 + wm * 64 + fi * 16 + lr4;
#pragma unroll
        for (int fj = 0; fj < 4; ++fj) {
            int c = col0 + wn * 64 + fj * 16 + lc;
            f32x4 v = acc[fi][fj];
            if (c < 1536) {                    // u: bias -> bf16
                float bv = bu[c];
#pragma unroll
                for (int g = 0; g < 4; ++g)
                    u[(size_t)(rb + g) * E + c] = f2bf(v[g] + bv);
            } else if (c < 3072) {             // v^T: out[b][cv][t], t contiguous
                int cv = c - 1536;
                float bv = bvp[cv];
                int b = rb >> 9, t0 = rb & 511;
                ushort4 o = {f2bf(v[0] + bv), f2bf(v[1] + bv),
                             f2bf(v[2] + bv), f2bf(v[3] + bv)};
                *(ushort4*)&vt[((size_t)b * E + cv) * 512 + t0] = o;
            } else {                           // z: bias -> f32
                int cz = c - 3072;
                float bv = bzp[cz];
#pragma unroll
                for (int g = 0; g < 4; ++g)
                    z[(size_t)(rb + g) * SD + cz] = v[g] + bv;
            }
        }
    }
}

extern "C" void kernel_launch(void* const* d_in, const int* in_sizes, int n_in,
                              void* d_out, int out_size, void* d_ws, size_t ws_size,
                              hipStream_t stream) {
    const int* tok = (const int*)d_in[0];
    const unsigned char* mask = (const unsigned char*)d_in[1];
    const float* embed = (const float*)d_in[2];
    const float* ln_g = (const float*)d_in[3];
    const float* ln_b = (const float*)d_in[4];
    const float* Wz = (const float*)d_in[5];
    const float* bz = (const float*)d_in[6];
    const float* gq = (const float*)d_in[7];
    const float* bq = (const float*)d_in[8];
    const float* gk = (const float*)d_in[9];
    const float* bk = (const float*)d_in[10];
    const float* Wu = (const float*)d_in[11];
    const float* bu = (const float*)d_in[12];
    const float* Wv = (const float*)d_in[13];
    const float* bv = (const float*)d_in[14];
    const float* Wo = (const float*)d_in[15];
    const float* bo = (const float*)d_in[16];
    const float* fin_g = (const float*)d_in[17];
    const float* fin_b = (const float*)d_in[18];

    char* wsb = (char*)d_ws;
    size_t off = 0;
    auto alloc = [&](size_t nbytes) {
        void* p = wsb + off;
        off = (off + nbytes + 255) & ~(size_t)255;
        return p;
    };
    int* flag = (int*)alloc(256);
    float* x = (float*)alloc((size_t)B * S * D * 4);
    unsigned short* xn = (unsigned short*)alloc((size_t)B * S * D * 2);
    float* z = (float*)alloc((size_t)B * S * SD * 4);
    unsigned short* q = (unsigned short*)alloc((size_t)B * S * SD * 2);
    unsigned short* k = (unsigned short*)alloc((size_t)B * S * SD * 2);
    unsigned short* u = (unsigned short*)alloc((size_t)B * S * E * 2);
    unsigned short* vt = (unsigned short*)alloc((size_t)B * E * S * 2);
    unsigned short* o = (unsigned short*)alloc((size_t)B * S * E * 2);
    unsigned short* a = (unsigned short*)alloc((size_t)B * S * S * 2);
    unsigned short* Wuvzt = (unsigned short*)alloc((size_t)L * 3200 * D * 2);
    unsigned short* Wot = (unsigned short*)alloc((size_t)L * D * E * 2);

    constexpr long WUVZ = 3200L * D;   // per-layer stride of concat weight

    detect_mask_kernel<<<1, 256, 0, stream>>>(mask, flag);
    embed_kernel<<<(B * S * D) / 256, 256, 0, stream>>>(tok, embed, x);
    tcast_kernel<<<dim3(D / 32, E / 32, L), dim3(32, 8), 0, stream>>>(Wu, Wuvzt, D, E, WUVZ);
    tcast_kernel<<<dim3(D / 32, E / 32, L), dim3(32, 8), 0, stream>>>(
        Wv, Wuvzt + 1536L * D, D, E, WUVZ);
    tcast_kernel<<<dim3(D / 32, SD / 32, L), dim3(32, 8), 0, stream>>>(
        Wz, Wuvzt + 3072L * D, D, SD, WUVZ);
    tcast_kernel<<<dim3(E / 32, D / 32, L), dim3(32, 8), 0, stream>>>(
        Wo, Wot, E, D, (long)D * E);

    for (int l = 0; l < L; ++l) {
        ln_kernel<true><<<B * S, 64, 0, stream>>>(x, ln_g + l * D, ln_b + l * D, xn);
        uvz_gemm<<<dim3(64, 25), 256, 0, stream>>>(
            xn, Wuvzt + (size_t)l * WUVZ, bu + l * E, bv + l * E, bz + l * SD, u, vt, z);
        qk_kernel<<<(B * S * SD) / 256, 256, 0, stream>>>(
            z, gq + (size_t)l * S * SD, bq + (size_t)l * S * SD,
            gk + (size_t)l * S * SD, bk + (size_t)l * S * SD, q, k);
        mgemm<3, 64, 64><<<dim3(8, 8, B), 256, 0, stream>>>(
            q, k, nullptr, mask, flag, a, S, SD,
            (long)S * SD, (long)S * SD, (long)S * S, S);
        mgemm<4, 128, 64><<<dim3(4, 24, B), 256, 0, stream>>>(
            a, vt, nullptr, u, nullptr, o, E, S,
            (long)S * S, (long)E * S, (long)S * E, (long)S * E);
        mgemm<5, 128, 64><<<dim3(64, 8), 256, 0, stream>>>(
            o, Wot + (size_t)l * D * E, bo + l * D, x, nullptr, x, D, E, 0, 0, 0, 0);
    }
    ln_kernel<false><<<B * S, 64, 0, stream>>>(x, fin_g, fin_b, (float*)d_out);
}

// Round 5
// 783.948 us; speedup vs baseline: 6.0665x; 1.0376x over previous
//
#include <hip/hip_runtime.h>
#include <hip/hip_bf16.h>
#include <stdint.h>

constexpr int L = 6, B = 16, S = 512, D = 512, SD = 128, E = 1536;

using bf16x8 = __attribute__((ext_vector_type(8))) short;
using f32x4  = __attribute__((ext_vector_type(4))) float;

typedef __attribute__((address_space(1))) void gvoid;
typedef __attribute__((address_space(3))) void lvoid;

__device__ __forceinline__ unsigned short f2bf(float f) {
    __hip_bfloat16 h = __float2bfloat16(f);
    return __builtin_bit_cast(unsigned short, h);
}
__device__ __forceinline__ float bf2f(unsigned short u) {
    unsigned int v = ((unsigned int)u) << 16;
    return __builtin_bit_cast(float, v);
}
__device__ __forceinline__ void gload16(const void* g, void* l) {
    __builtin_amdgcn_global_load_lds((gvoid*)g, (lvoid*)l, 16, 0, 0);
}

// bijective XCD-chunk swizzle (requires total blocks % 8 == 0).
// y-fastest decomposition so each XCD chunk shares A-row panels / batches.
__device__ __forceinline__ void swz_bid(int& bx, int& by, int& bz) {
    int gx = gridDim.x, gy = gridDim.y, gz = gridDim.z;
    int n = gx * gy * gz;
    int id = blockIdx.x + gx * (blockIdx.y + gy * blockIdx.z);
    int id2 = (id & 7) * (n >> 3) + (id >> 3);
    by = id2 % gy;
    int t = id2 / gy;
    bx = t % gx;
    bz = t / gx;
}

// ---------------- mask layout detection ----------------
__global__ void detect_mask_kernel(const unsigned char* __restrict__ m, int* flag) {
    if (threadIdx.x == 0) *flag = 0;
    __syncthreads();
    int any = 0;
    for (int i = threadIdx.x; i < B * S; i += blockDim.x)
        if ((i & 3) != 0 && m[i] != 0) any = 1;
    if (any) atomicOr(flag, 1);
}

// ---------------- embedding + positional encoding ----------------
__global__ void embed_kernel(const int* __restrict__ tok, const float* __restrict__ embed,
                             float* __restrict__ x) {
    int idx = blockIdx.x * blockDim.x + threadIdx.x;      // over B*S*D
    int d = idx & (D - 1);
    int bs = idx >> 9;                                    // D = 512 = 2^9
    int s = bs & (S - 1);
    float e = embed[(size_t)tok[bs] * D + d] * 22.62741699796952f;  // sqrt(512)
    float expo = (float)(d >> 1) * (1.0f / 256.0f);
    float ang = (float)s * expf(expo * -9.210340371976184f);
    float pe = (d & 1) ? cosf(ang) : sinf(ang);
    x[idx] = e + pe;
}

// ---- weight transpose + cast: W (K x N f32) -> Wt (N x K bf16), per-layer out stride ----
__global__ __launch_bounds__(256) void tcast_kernel(const float* __restrict__ W,
                                                    unsigned short* __restrict__ Wt,
                                                    int K, int N, long ostride) {
    __shared__ float t[32][33];
    W  += (size_t)blockIdx.z * K * N;
    Wt += (size_t)blockIdx.z * ostride;
    int k0 = blockIdx.x * 32, n0 = blockIdx.y * 32;
    int tx = threadIdx.x, ty = threadIdx.y;               // 32 x 8
#pragma unroll
    for (int i = 0; i < 4; ++i)
        t[ty + i * 8][tx] = W[(size_t)(k0 + ty + i * 8) * N + n0 + tx];
    __syncthreads();
#pragma unroll
    for (int i = 0; i < 4; ++i)
        Wt[(size_t)(n0 + ty + i * 8) * K + k0 + tx] = f2bf(t[tx][ty + i * 8]);
}

// ---------------- layernorm: one wave per row of D=512 ----------------
template <bool BF>
__global__ __launch_bounds__(64) void ln_kernel(const float* __restrict__ x,
                                                const float* __restrict__ g,
                                                const float* __restrict__ b,
                                                void* __restrict__ yp) {
    int row = blockIdx.x;
    int lane = threadIdx.x;
    const float* xr = x + (size_t)row * D;
    float4 v0 = *(const float4*)(xr + lane * 4);
    float4 v1 = *(const float4*)(xr + 256 + lane * 4);
    float sum = v0.x + v0.y + v0.z + v0.w + v1.x + v1.y + v1.z + v1.w;
#pragma unroll
    for (int o = 1; o < 64; o <<= 1) sum += __shfl_xor(sum, o);
    float m = sum * (1.0f / D);
    float d0 = v0.x - m, d1 = v0.y - m, d2 = v0.z - m, d3 = v0.w - m;
    float e0 = v1.x - m, e1 = v1.y - m, e2 = v1.z - m, e3 = v1.w - m;
    float sq = d0 * d0 + d1 * d1 + d2 * d2 + d3 * d3 + e0 * e0 + e1 * e1 + e2 * e2 + e3 * e3;
#pragma unroll
    for (int o = 1; o < 64; o <<= 1) sq += __shfl_xor(sq, o);
    float inv = rsqrtf(sq * (1.0f / D) + 1e-5f);
    int c0 = lane * 4, c1 = 256 + lane * 4;
    float4 g0 = *(const float4*)(g + c0), g1 = *(const float4*)(g + c1);
    float4 b0 = *(const float4*)(b + c0), b1 = *(const float4*)(b + c1);
    float o0 = d0 * inv * g0.x + b0.x, o1 = d1 * inv * g0.y + b0.y;
    float o2 = d2 * inv * g0.z + b0.z, o3 = d3 * inv * g0.w + b0.w;
    float o4 = e0 * inv * g1.x + b1.x, o5 = e1 * inv * g1.y + b1.y;
    float o6 = e2 * inv * g1.z + b1.z, o7 = e3 * inv * g1.w + b1.w;
    if constexpr (BF) {
        unsigned short* yr = (unsigned short*)yp + (size_t)row * D;
        ushort4 p0 = {f2bf(o0), f2bf(o1), f2bf(o2), f2bf(o3)};
        ushort4 p1 = {f2bf(o4), f2bf(o5), f2bf(o6), f2bf(o7)};
        *(ushort4*)(yr + c0) = p0;
        *(ushort4*)(yr + c1) = p1;
    } else {
        float* yr = (float*)yp + (size_t)row * D;
        float4 p0 = {o0, o1, o2, o3}, p1 = {o4, o5, o6, o7};
        *(float4*)(yr + c0) = p0;
        *(float4*)(yr + c1) = p1;
    }
}

// ---------------- MFMA GEMM core: tile BM x BN, BK=64, 4 waves (2x2) ----------------
// LDS tiles [rows][64] bf16, chunk-XOR swizzle: phys_chunk = log_chunk ^ (row&7).
// Staging via global_load_lds(16B), pre-swizzled per-lane global source.
// SWAP=true: acc = mfma(bF, aF, acc) -> per-lane regs walk the N (col) dimension:
//   out row = lane&15 (+frag), out col = (lane>>4)*4 + reg (+frag)  => coalesced stores.
template <int BM, int BN, bool SWAP>
__device__ __forceinline__ void gemm_core(const unsigned short* __restrict__ Ab,
                                          const unsigned short* __restrict__ Bb,
                                          int K, short* lsA, short* lsB,
                                          f32x4 (&acc)[BM / 32][BN / 32],
                                          int lane, int wv) {
    constexpr int NA = BM / 32, NB = BN / 32;
    constexpr int FM = BM / 32, FN = BN / 32;
    constexpr int WTM = BM / 2, WTN = BN / 2;
    const int wm = wv >> 1, wn = wv & 1;
    const unsigned short* ga[NA]; int lofsA[NA];
    const unsigned short* gb[NB]; int lofsB[NB];
#pragma unroll
    for (int i = 0; i < NA; ++i) {
        int s = wv * NA + i;
        int r = s * 8 + (lane >> 3);
        int cl = (lane & 7) ^ (r & 7);
        ga[i] = Ab + (size_t)r * K + cl * 8;
        lofsA[i] = s * 512;
    }
#pragma unroll
    for (int i = 0; i < NB; ++i) {
        int s = wv * NB + i;
        int r = s * 8 + (lane >> 3);
        int cl = (lane & 7) ^ (r & 7);
        gb[i] = Bb + (size_t)r * K + cl * 8;
        lofsB[i] = s * 512;
    }
    const int nkt = K >> 6;
    for (int kt = 0; kt < nkt; ++kt) {
        if (kt) __syncthreads();
#pragma unroll
        for (int i = 0; i < NA; ++i) gload16(ga[i] + kt * 64, (void*)&lsA[lofsA[i]]);
#pragma unroll
        for (int i = 0; i < NB; ++i) gload16(gb[i] + kt * 64, (void*)&lsB[lofsB[i]]);
        __syncthreads();
#pragma unroll
        for (int ks = 0; ks < 2; ++ks) {
            bf16x8 aF[FM], bF[FN];
#pragma unroll
            for (int f = 0; f < FM; ++f) {
                int ra = wm * WTM + f * 16 + (lane & 15);
                int ca = (ks * 4 + (lane >> 4)) ^ (ra & 7);
                aF[f] = *(const bf16x8*)&lsA[ra * 64 + ca * 8];
            }
#pragma unroll
            for (int f = 0; f < FN; ++f) {
                int rb = wn * WTN + f * 16 + (lane & 15);
                int cb = (ks * 4 + (lane >> 4)) ^ (rb & 7);
                bF[f] = *(const bf16x8*)&lsB[rb * 64 + cb * 8];
            }
#pragma unroll
            for (int fi = 0; fi < FM; ++fi)
#pragma unroll
                for (int fj = 0; fj < FN; ++fj) {
                    if constexpr (SWAP)
                        acc[fi][fj] = __builtin_amdgcn_mfma_f32_16x16x32_bf16(
                            bF[fj], aF[fi], acc[fi][fj], 0, 0, 0);
                    else
                        acc[fi][fj] = __builtin_amdgcn_mfma_f32_16x16x32_bf16(
                            aF[fi], bF[fj], acc[fi][fj], 0, 0, 0);
                }
        }
    }
}

// ---------------- fused u|v|z GEMM over xn(8192x512), region-split -----------------
// REGION 0: u (swap, bias->bf16 row-major), 1: v^T (noswap, along-t stores),
// REGION 2: z fused with q/k elementwise (swap): q=z*gq+bq, k=z*gk+bk, bf16.
template <int REGION>
__global__ __launch_bounds__(256) void uvz_gemm(const unsigned short* __restrict__ xn,
                                                const unsigned short* __restrict__ Bt,
                                                const float* __restrict__ bias,
                                                const float* __restrict__ gq,
                                                const float* __restrict__ bq,
                                                const float* __restrict__ gk,
                                                const float* __restrict__ bk,
                                                unsigned short* __restrict__ o0,
                                                unsigned short* __restrict__ o1) {
    __shared__ short lsA[128 * 64];
    __shared__ short lsB[128 * 64];
    int bx, by, bzz;
    swz_bid(bx, by, bzz);
    const int tid = threadIdx.x;
    const int lane = tid & 63, wv = tid >> 6;
    const int wm = wv >> 1, wn = wv & 1;
    const int row0 = bx * 128, col0 = by * 128;
    const unsigned short* Ab = xn + (size_t)row0 * D;
    const unsigned short* Bb = Bt + (size_t)col0 * D;

    f32x4 acc[4][4] = {};
    gemm_core<128, 128, (REGION != 1)>(Ab, Bb, D, lsA, lsB, acc, lane, wv);

    const int lr4 = (lane >> 4) * 4;
    const int lc = lane & 15;
#pragma unroll
    for (int fi = 0; fi < 4; ++fi) {
#pragma unroll
        for (int fj = 0; fj < 4; ++fj) {
            f32x4 v = acc[fi][fj];
            if constexpr (REGION == 0) {         // u: row-major bf16
                int r = row0 + wm * 64 + fi * 16 + lc;
                int cb = col0 + wn * 64 + fj * 16 + lr4;
                f32x4 bv = *(const f32x4*)&bias[cb];
                ushort4 ov = {f2bf(v[0] + bv[0]), f2bf(v[1] + bv[1]),
                              f2bf(v[2] + bv[2]), f2bf(v[3] + bv[3])};
                *(ushort4*)&o0[(size_t)r * E + cb] = ov;
            } else if constexpr (REGION == 1) {  // v^T: out[b][c][t], t contiguous
                int rb = row0 + wm * 64 + fi * 16 + lr4;
                int c = col0 + wn * 64 + fj * 16 + lc;
                float bv = bias[c];
                int b = rb >> 9, t0 = rb & 511;
                ushort4 ov = {f2bf(v[0] + bv), f2bf(v[1] + bv),
                              f2bf(v[2] + bv), f2bf(v[3] + bv)};
                *(ushort4*)&o0[((size_t)b * E + c) * 512 + t0] = ov;
            } else {                             // z -> q,k fused
                int r = row0 + wm * 64 + fi * 16 + lc;
                int cb = wn * 64 + fj * 16 + lr4;   // col0 == 0 (single col-block)
                int s = r & 511;
                f32x4 bz4 = *(const f32x4*)&bias[cb];
                f32x4 gq4 = *(const f32x4*)&gq[(size_t)s * SD + cb];
                f32x4 bq4 = *(const f32x4*)&bq[(size_t)s * SD + cb];
                f32x4 gk4 = *(const f32x4*)&gk[(size_t)s * SD + cb];
                f32x4 bk4 = *(const f32x4*)&bk[(size_t)s * SD + cb];
                ushort4 qv, kv;
#pragma unroll
                for (int g = 0; g < 4; ++g) {
                    float zz = v[g] + bz4[g];
                    ((unsigned short*)&qv)[g] = f2bf(fmaf(zz, gq4[g], bq4[g]));
                    ((unsigned short*)&kv)[g] = f2bf(fmaf(zz, gk4[g], bk4[g]));
                }
                *(ushort4*)&o0[(size_t)r * SD + cb] = qv;
                *(ushort4*)&o1[(size_t)r * SD + cb] = kv;
            }
        }
    }
}

// EPI: 3 relu^2+mask->bf16 | 4 u*acc->bf16 | 5 bias+residual->f32   (all SWAP layout)
template <int EPI, int BM, int BN>
__global__ __launch_bounds__(256) void mgemm(const unsigned short* __restrict__ A,
                                             const unsigned short* __restrict__ Bt,
                                             const float* __restrict__ bias,
                                             const void* __restrict__ aux,
                                             const int* __restrict__ flagp,
                                             void* __restrict__ Cp,
                                             int N, int K,
                                             long sA, long sB, long sC, long sAux) {
    __shared__ short lsA[BM * 64];
    __shared__ short lsB[BN * 64];
    constexpr int FM = BM / 32, FN = BN / 32;
    int bx, by, bz;
    swz_bid(bx, by, bz);
    const int tid = threadIdx.x;
    const int lane = tid & 63, wv = tid >> 6;
    const int wm = wv >> 1, wn = wv & 1;
    const int row0 = bx * BM, col0 = by * BN;

    const unsigned short* Ab = A + (size_t)bz * sA + (size_t)row0 * K;
    const unsigned short* Bb = Bt + (size_t)bz * sB + (size_t)col0 * K;

    f32x4 acc[FM][FN] = {};
    gemm_core<BM, BN, true>(Ab, Bb, K, lsA, lsB, acc, lane, wv);

    const int lr4 = (lane >> 4) * 4;
    const int lc = lane & 15;
#pragma unroll
    for (int fi = 0; fi < FM; ++fi) {
        int r = row0 + wm * (BM / 2) + fi * 16 + lc;
#pragma unroll
        for (int fj = 0; fj < FN; ++fj) {
            int cb = col0 + wn * (BN / 2) + fj * 16 + lr4;
            f32x4 v = acc[fi][fj];
            if constexpr (EPI == 3) {   // relu^2 + key mask (cols = keys t)
                unsigned short* C = (unsigned short*)Cp + (size_t)bz * sC;
                int flag = *flagp;
                ushort4 ov;
#pragma unroll
                for (int g = 0; g < 4; ++g) {
                    int c = cb + g;
                    int mv = flag ? (int)((const unsigned char*)aux)[bz * sAux + c]
                                  : ((const int*)aux)[bz * sAux + c];
                    float vv = fmaxf(v[g], 0.0f);
                    vv *= vv;
                    ((unsigned short*)&ov)[g] = mv ? (unsigned short)0 : f2bf(vv);
                }
                *(ushort4*)&C[(size_t)r * N + cb] = ov;
            } else if constexpr (EPI == 4) {   // o = u * (a@v)
                const unsigned short* U = (const unsigned short*)aux + (size_t)bz * sAux;
                unsigned short* C = (unsigned short*)Cp + (size_t)bz * sC;
                size_t off = (size_t)r * N + cb;
                ushort4 uu = *(const ushort4*)&U[off];
                ushort4 ov = {f2bf(bf2f(uu.x) * v[0]), f2bf(bf2f(uu.y) * v[1]),
                              f2bf(bf2f(uu.z) * v[2]), f2bf(bf2f(uu.w) * v[3])};
                *(ushort4*)&C[off] = ov;
            } else {                           // EPI 5: bias + residual, f32 in-place
                float* C = (float*)Cp;
                const float* X = (const float*)aux;
                size_t off = (size_t)r * N + cb;
                f32x4 bb = *(const f32x4*)&bias[cb];
                f32x4 xx = *(const f32x4*)&X[off];
                f32x4 ov = {v[0] + bb[0] + xx[0], v[1] + bb[1] + xx[1],
                            v[2] + bb[2] + xx[2], v[3] + bb[3] + xx[3]};
                *(f32x4*)&C[off] = ov;
            }
        }
    }
}

extern "C" void kernel_launch(void* const* d_in, const int* in_sizes, int n_in,
                              void* d_out, int out_size, void* d_ws, size_t ws_size,
                              hipStream_t stream) {
    const int* tok = (const int*)d_in[0];
    const unsigned char* mask = (const unsigned char*)d_in[1];
    const float* embed = (const float*)d_in[2];
    const float* ln_g = (const float*)d_in[3];
    const float* ln_b = (const float*)d_in[4];
    const float* Wz = (const float*)d_in[5];
    const float* bz = (const float*)d_in[6];
    const float* gq = (const float*)d_in[7];
    const float* bq = (const float*)d_in[8];
    const float* gk = (const float*)d_in[9];
    const float* bk = (const float*)d_in[10];
    const float* Wu = (const float*)d_in[11];
    const float* bu = (const float*)d_in[12];
    const float* Wv = (const float*)d_in[13];
    const float* bv = (const float*)d_in[14];
    const float* Wo = (const float*)d_in[15];
    const float* bo = (const float*)d_in[16];
    const float* fin_g = (const float*)d_in[17];
    const float* fin_b = (const float*)d_in[18];

    char* wsb = (char*)d_ws;
    size_t off = 0;
    auto alloc = [&](size_t nbytes) {
        void* p = wsb + off;
        off = (off + nbytes + 255) & ~(size_t)255;
        return p;
    };
    int* flag = (int*)alloc(256);
    float* x = (float*)alloc((size_t)B * S * D * 4);
    unsigned short* xn = (unsigned short*)alloc((size_t)B * S * D * 2);
    unsigned short* q = (unsigned short*)alloc((size_t)B * S * SD * 2);
    unsigned short* k = (unsigned short*)alloc((size_t)B * S * SD * 2);
    unsigned short* u = (unsigned short*)alloc((size_t)B * S * E * 2);
    unsigned short* vt = (unsigned short*)alloc((size_t)B * E * S * 2);
    unsigned short* o = (unsigned short*)alloc((size_t)B * S * E * 2);
    unsigned short* a = (unsigned short*)alloc((size_t)B * S * S * 2);
    unsigned short* Wuvzt = (unsigned short*)alloc((size_t)L * 3200 * D * 2);
    unsigned short* Wot = (unsigned short*)alloc((size_t)L * D * E * 2);

    constexpr long WUVZ = 3200L * D;   // per-layer stride of concat weight

    detect_mask_kernel<<<1, 256, 0, stream>>>(mask, flag);
    embed_kernel<<<(B * S * D) / 256, 256, 0, stream>>>(tok, embed, x);
    tcast_kernel<<<dim3(D / 32, E / 32, L), dim3(32, 8), 0, stream>>>(Wu, Wuvzt, D, E, WUVZ);
    tcast_kernel<<<dim3(D / 32, E / 32, L), dim3(32, 8), 0, stream>>>(
        Wv, Wuvzt + 1536L * D, D, E, WUVZ);
    tcast_kernel<<<dim3(D / 32, SD / 32, L), dim3(32, 8), 0, stream>>>(
        Wz, Wuvzt + 3072L * D, D, SD, WUVZ);
    tcast_kernel<<<dim3(E / 32, D / 32, L), dim3(32, 8), 0, stream>>>(
        Wo, Wot, E, D, (long)D * E);

    for (int l = 0; l < L; ++l) {
        ln_kernel<true><<<B * S, 64, 0, stream>>>(x, ln_g + l * D, ln_b + l * D, xn);
        uvz_gemm<0><<<dim3(64, 12), 256, 0, stream>>>(
            xn, Wuvzt + (size_t)l * WUVZ, bu + l * E,
            nullptr, nullptr, nullptr, nullptr, u, nullptr);
        uvz_gemm<1><<<dim3(64, 12), 256, 0, stream>>>(
            xn, Wuvzt + (size_t)l * WUVZ + 1536L * D, bv + l * E,
            nullptr, nullptr, nullptr, nullptr, vt, nullptr);
        uvz_gemm<2><<<dim3(64, 1), 256, 0, stream>>>(
            xn, Wuvzt + (size_t)l * WUVZ + 3072L * D, bz + l * SD,
            gq + (size_t)l * S * SD, bq + (size_t)l * S * SD,
            gk + (size_t)l * S * SD, bk + (size_t)l * S * SD, q, k);
        mgemm<3, 64, 64><<<dim3(8, 8, B), 256, 0, stream>>>(
            q, k, nullptr, mask, flag, a, S, SD,
            (long)S * SD, (long)S * SD, (long)S * S, S);
        mgemm<4, 128, 64><<<dim3(4, 24, B), 256, 0, stream>>>(
            a, vt, nullptr, u, nullptr, o, E, S,
            (long)S * S, (long)E * S, (long)S * E, (long)S * E);
        mgemm<5, 128, 64><<<dim3(64, 8), 256, 0, stream>>>(
            o, Wot + (size_t)l * D * E, bo + l * D, x, nullptr, x, D, E, 0, 0, 0, 0);
    }
    ln_kernel<false><<<B * S, 64, 0, stream>>>(x, fin_g, fin_b, (float*)d_out);
}

// Round 6
// 769.533 us; speedup vs baseline: 6.1801x; 1.0187x over previous
//
#include <hip/hip_runtime.h>
#include <hip/hip_bf16.h>
#include <stdint.h>

constexpr int L = 6, B = 16, S = 512, D = 512, SD = 128, E = 1536;

using bf16x8 = __attribute__((ext_vector_type(8))) short;
using f32x4  = __attribute__((ext_vector_type(4))) float;

typedef __attribute__((address_space(1))) void gvoid;
typedef __attribute__((address_space(3))) void lvoid;

__device__ __forceinline__ unsigned short f2bf(float f) {
    __hip_bfloat16 h = __float2bfloat16(f);
    return __builtin_bit_cast(unsigned short, h);
}
__device__ __forceinline__ float bf2f(unsigned short u) {
    unsigned int v = ((unsigned int)u) << 16;
    return __builtin_bit_cast(float, v);
}
__device__ __forceinline__ void gload16(const void* g, void* l) {
    __builtin_amdgcn_global_load_lds((gvoid*)g, (lvoid*)l, 16, 0, 0);
}

// bijective XCD-chunk swizzle (requires total blocks % 8 == 0).
__device__ __forceinline__ void swz_bid(int& bx, int& by, int& bz) {
    int gx = gridDim.x, gy = gridDim.y, gz = gridDim.z;
    int n = gx * gy * gz;
    int id = blockIdx.x + gx * (blockIdx.y + gy * blockIdx.z);
    int id2 = (id & 7) * (n >> 3) + (id >> 3);
    by = id2 % gy;
    int t = id2 / gy;
    bx = t % gx;
    bz = t / gx;
}

// ---------------- mask layout detection ----------------
__global__ void detect_mask_kernel(const unsigned char* __restrict__ m, int* flag) {
    if (threadIdx.x == 0) *flag = 0;
    __syncthreads();
    int any = 0;
    for (int i = threadIdx.x; i < B * S; i += blockDim.x)
        if ((i & 3) != 0 && m[i] != 0) any = 1;
    if (any) atomicOr(flag, 1);
}

// ---------------- embedding + positional encoding ----------------
__global__ void embed_kernel(const int* __restrict__ tok, const float* __restrict__ embed,
                             float* __restrict__ x) {
    int idx = blockIdx.x * blockDim.x + threadIdx.x;      // over B*S*D
    int d = idx & (D - 1);
    int bs = idx >> 9;                                    // D = 512 = 2^9
    int s = bs & (S - 1);
    float e = embed[(size_t)tok[bs] * D + d] * 22.62741699796952f;  // sqrt(512)
    float expo = (float)(d >> 1) * (1.0f / 256.0f);
    float ang = (float)s * expf(expo * -9.210340371976184f);
    float pe = (d & 1) ? cosf(ang) : sinf(ang);
    x[idx] = e + pe;
}

// ---- weight transpose + cast: W (K x N f32) -> Wt (N x K bf16), per-layer out stride ----
__global__ __launch_bounds__(256) void tcast_kernel(const float* __restrict__ W,
                                                    unsigned short* __restrict__ Wt,
                                                    int K, int N, long ostride) {
    __shared__ float t[32][33];
    W  += (size_t)blockIdx.z * K * N;
    Wt += (size_t)blockIdx.z * ostride;
    int k0 = blockIdx.x * 32, n0 = blockIdx.y * 32;
    int tx = threadIdx.x, ty = threadIdx.y;               // 32 x 8
#pragma unroll
    for (int i = 0; i < 4; ++i)
        t[ty + i * 8][tx] = W[(size_t)(k0 + ty + i * 8) * N + n0 + tx];
    __syncthreads();
#pragma unroll
    for (int i = 0; i < 4; ++i)
        Wt[(size_t)(n0 + ty + i * 8) * K + k0 + tx] = f2bf(t[tx][ty + i * 8]);
}

// ---------------- layernorm: 4 rows/block, one wave per row of D=512 ----------------
template <bool BF>
__global__ __launch_bounds__(256) void ln_kernel(const float* __restrict__ x,
                                                 const float* __restrict__ g,
                                                 const float* __restrict__ b,
                                                 void* __restrict__ yp) {
    int row = blockIdx.x * 4 + (threadIdx.x >> 6);
    int lane = threadIdx.x & 63;
    const float* xr = x + (size_t)row * D;
    float4 v0 = *(const float4*)(xr + lane * 4);
    float4 v1 = *(const float4*)(xr + 256 + lane * 4);
    float sum = v0.x + v0.y + v0.z + v0.w + v1.x + v1.y + v1.z + v1.w;
#pragma unroll
    for (int o = 1; o < 64; o <<= 1) sum += __shfl_xor(sum, o);
    float m = sum * (1.0f / D);
    float d0 = v0.x - m, d1 = v0.y - m, d2 = v0.z - m, d3 = v0.w - m;
    float e0 = v1.x - m, e1 = v1.y - m, e2 = v1.z - m, e3 = v1.w - m;
    float sq = d0 * d0 + d1 * d1 + d2 * d2 + d3 * d3 + e0 * e0 + e1 * e1 + e2 * e2 + e3 * e3;
#pragma unroll
    for (int o = 1; o < 64; o <<= 1) sq += __shfl_xor(sq, o);
    float inv = rsqrtf(sq * (1.0f / D) + 1e-5f);
    int c0 = lane * 4, c1 = 256 + lane * 4;
    float4 g0 = *(const float4*)(g + c0), g1 = *(const float4*)(g + c1);
    float4 b0 = *(const float4*)(b + c0), b1 = *(const float4*)(b + c1);
    float o0 = d0 * inv * g0.x + b0.x, o1 = d1 * inv * g0.y + b0.y;
    float o2 = d2 * inv * g0.z + b0.z, o3 = d3 * inv * g0.w + b0.w;
    float o4 = e0 * inv * g1.x + b1.x, o5 = e1 * inv * g1.y + b1.y;
    float o6 = e2 * inv * g1.z + b1.z, o7 = e3 * inv * g1.w + b1.w;
    if constexpr (BF) {
        unsigned short* yr = (unsigned short*)yp + (size_t)row * D;
        ushort4 p0 = {f2bf(o0), f2bf(o1), f2bf(o2), f2bf(o3)};
        ushort4 p1 = {f2bf(o4), f2bf(o5), f2bf(o6), f2bf(o7)};
        *(ushort4*)(yr + c0) = p0;
        *(ushort4*)(yr + c1) = p1;
    } else {
        float* yr = (float*)yp + (size_t)row * D;
        float4 p0 = {o0, o1, o2, o3}, p1 = {o4, o5, o6, o7};
        *(float4*)(yr + c0) = p0;
        *(float4*)(yr + c1) = p1;
    }
}

// ---------------- MFMA GEMM core: tile BM x BN, BK=64, 4 waves (2x2) ----------------
// LDS tiles [rows][64] bf16, chunk-XOR swizzle: phys_chunk = log_chunk ^ (row&7).
// Staging via global_load_lds(16B), pre-swizzled per-lane global source.
// SWAP=true: acc = mfma(bF, aF, acc) -> per-lane regs walk the N (col) dimension:
//   out row = lane&15 (+frag), out col = (lane>>4)*4 + reg (+frag)  => coalesced stores.
template <int BM, int BN, bool SWAP>
__device__ __forceinline__ void gemm_core(const unsigned short* __restrict__ Ab,
                                          const unsigned short* __restrict__ Bb,
                                          int K, short* lsA, short* lsB,
                                          f32x4 (&acc)[BM / 32][BN / 32],
                                          int lane, int wv) {
    constexpr int NA = BM / 32, NB = BN / 32;
    constexpr int FM = BM / 32, FN = BN / 32;
    constexpr int WTM = BM / 2, WTN = BN / 2;
    const int wm = wv >> 1, wn = wv & 1;
    const unsigned short* ga[NA]; int lofsA[NA];
    const unsigned short* gb[NB]; int lofsB[NB];
#pragma unroll
    for (int i = 0; i < NA; ++i) {
        int s = wv * NA + i;
        int r = s * 8 + (lane >> 3);
        int cl = (lane & 7) ^ (r & 7);
        ga[i] = Ab + (size_t)r * K + cl * 8;
        lofsA[i] = s * 512;
    }
#pragma unroll
    for (int i = 0; i < NB; ++i) {
        int s = wv * NB + i;
        int r = s * 8 + (lane >> 3);
        int cl = (lane & 7) ^ (r & 7);
        gb[i] = Bb + (size_t)r * K + cl * 8;
        lofsB[i] = s * 512;
    }
    const int nkt = K >> 6;
    for (int kt = 0; kt < nkt; ++kt) {
        if (kt) __syncthreads();
#pragma unroll
        for (int i = 0; i < NA; ++i) gload16(ga[i] + kt * 64, (void*)&lsA[lofsA[i]]);
#pragma unroll
        for (int i = 0; i < NB; ++i) gload16(gb[i] + kt * 64, (void*)&lsB[lofsB[i]]);
        __syncthreads();
#pragma unroll
        for (int ks = 0; ks < 2; ++ks) {
            bf16x8 aF[FM], bF[FN];
#pragma unroll
            for (int f = 0; f < FM; ++f) {
                int ra = wm * WTM + f * 16 + (lane & 15);
                int ca = (ks * 4 + (lane >> 4)) ^ (ra & 7);
                aF[f] = *(const bf16x8*)&lsA[ra * 64 + ca * 8];
            }
#pragma unroll
            for (int f = 0; f < FN; ++f) {
                int rb = wn * WTN + f * 16 + (lane & 15);
                int cb = (ks * 4 + (lane >> 4)) ^ (rb & 7);
                bF[f] = *(const bf16x8*)&lsB[rb * 64 + cb * 8];
            }
#pragma unroll
            for (int fi = 0; fi < FM; ++fi)
#pragma unroll
                for (int fj = 0; fj < FN; ++fj) {
                    if constexpr (SWAP)
                        acc[fi][fj] = __builtin_amdgcn_mfma_f32_16x16x32_bf16(
                            bF[fj], aF[fi], acc[fi][fj], 0, 0, 0);
                    else
                        acc[fi][fj] = __builtin_amdgcn_mfma_f32_16x16x32_bf16(
                            aF[fi], bF[fj], acc[fi][fj], 0, 0, 0);
                }
        }
    }
}

// ---------------- fused u|v GEMM over xn(8192x512): grid (64, 12, 2) ----------------
// bz=0: u = xn@Wu+bu -> bf16 row-major (SWAP). bz=1: v^T[b][c][t] (NOSWAP).
__global__ __launch_bounds__(256) void uv_gemm(const unsigned short* __restrict__ xn,
                                               const unsigned short* __restrict__ Wuvt,
                                               const float* __restrict__ bu,
                                               const float* __restrict__ bvp,
                                               unsigned short* __restrict__ u,
                                               unsigned short* __restrict__ vt) {
    __shared__ short lsA[128 * 64];
    __shared__ short lsB[128 * 64];
    int bx, by, bz;
    swz_bid(bx, by, bz);
    const int tid = threadIdx.x;
    const int lane = tid & 63, wv = tid >> 6;
    const int wm = wv >> 1, wn = wv & 1;
    const int row0 = bx * 128, col0 = by * 128;
    const unsigned short* Ab = xn + (size_t)row0 * D;
    const unsigned short* Bb = Wuvt + ((size_t)bz * E + col0) * D;

    const int lr4 = (lane >> 4) * 4;
    const int lc = lane & 15;
    if (bz == 0) {
        f32x4 acc[4][4] = {};
        gemm_core<128, 128, true>(Ab, Bb, D, lsA, lsB, acc, lane, wv);
#pragma unroll
        for (int fi = 0; fi < 4; ++fi) {
            int r = row0 + wm * 64 + fi * 16 + lc;
#pragma unroll
            for (int fj = 0; fj < 4; ++fj) {
                int cb = col0 + wn * 64 + fj * 16 + lr4;
                f32x4 v = acc[fi][fj];
                f32x4 bv = *(const f32x4*)&bu[cb];
                ushort4 ov = {f2bf(v[0] + bv[0]), f2bf(v[1] + bv[1]),
                              f2bf(v[2] + bv[2]), f2bf(v[3] + bv[3])};
                *(ushort4*)&u[(size_t)r * E + cb] = ov;
            }
        }
    } else {
        f32x4 acc[4][4] = {};
        gemm_core<128, 128, false>(Ab, Bb, D, lsA, lsB, acc, lane, wv);
#pragma unroll
        for (int fi = 0; fi < 4; ++fi) {
            int rb = row0 + wm * 64 + fi * 16 + lr4;
#pragma unroll
            for (int fj = 0; fj < 4; ++fj) {
                int c = col0 + wn * 64 + fj * 16 + lc;
                f32x4 v = acc[fi][fj];
                float bv = bvp[c];
                int b = rb >> 9, t0 = rb & 511;
                ushort4 ov = {f2bf(v[0] + bv), f2bf(v[1] + bv),
                              f2bf(v[2] + bv), f2bf(v[3] + bv)};
                *(ushort4*)&vt[((size_t)b * E + c) * 512 + t0] = ov;
            }
        }
    }
}

// ---------------- z GEMM fused with q/k elementwise (SWAP): grid (64,1) -----------
__global__ __launch_bounds__(256) void zqk_gemm(const unsigned short* __restrict__ xn,
                                                const unsigned short* __restrict__ Bt,
                                                const float* __restrict__ bias,
                                                const float* __restrict__ gq,
                                                const float* __restrict__ bq,
                                                const float* __restrict__ gk,
                                                const float* __restrict__ bk,
                                                unsigned short* __restrict__ q,
                                                unsigned short* __restrict__ k) {
    __shared__ short lsA[128 * 64];
    __shared__ short lsB[128 * 64];
    int bx, by, bz;
    swz_bid(bx, by, bz);
    const int tid = threadIdx.x;
    const int lane = tid & 63, wv = tid >> 6;
    const int wm = wv >> 1, wn = wv & 1;
    const int row0 = bx * 128;
    const unsigned short* Ab = xn + (size_t)row0 * D;

    f32x4 acc[4][4] = {};
    gemm_core<128, 128, true>(Ab, Bt, D, lsA, lsB, acc, lane, wv);

    const int lr4 = (lane >> 4) * 4;
    const int lc = lane & 15;
#pragma unroll
    for (int fi = 0; fi < 4; ++fi) {
        int r = row0 + wm * 64 + fi * 16 + lc;
        int s = r & 511;
#pragma unroll
        for (int fj = 0; fj < 4; ++fj) {
            int cb = wn * 64 + fj * 16 + lr4;
            f32x4 v = acc[fi][fj];
            f32x4 bz4 = *(const f32x4*)&bias[cb];
            f32x4 gq4 = *(const f32x4*)&gq[(size_t)s * SD + cb];
            f32x4 bq4 = *(const f32x4*)&bq[(size_t)s * SD + cb];
            f32x4 gk4 = *(const f32x4*)&gk[(size_t)s * SD + cb];
            f32x4 bk4 = *(const f32x4*)&bk[(size_t)s * SD + cb];
            ushort4 qv, kv;
#pragma unroll
            for (int g = 0; g < 4; ++g) {
                float zz = v[g] + bz4[g];
                ((unsigned short*)&qv)[g] = f2bf(fmaf(zz, gq4[g], bq4[g]));
                ((unsigned short*)&kv)[g] = f2bf(fmaf(zz, gk4[g], bk4[g]));
            }
            *(ushort4*)&q[(size_t)r * SD + cb] = qv;
            *(ushort4*)&k[(size_t)r * SD + cb] = kv;
        }
    }
}

// EPI: 3 relu^2+mask->bf16 | 4 u*acc->bf16 | 5 bias+residual->f32   (all SWAP layout)
template <int EPI, int BM, int BN>
__global__ __launch_bounds__(256) void mgemm(const unsigned short* __restrict__ A,
                                             const unsigned short* __restrict__ Bt,
                                             const float* __restrict__ bias,
                                             const void* __restrict__ aux,
                                             const int* __restrict__ flagp,
                                             void* __restrict__ Cp,
                                             int N, int K,
                                             long sA, long sB, long sC, long sAux) {
    __shared__ short lsA[BM * 64];
    __shared__ short lsB[BN * 64];
    constexpr int FM = BM / 32, FN = BN / 32;
    int bx, by, bz;
    swz_bid(bx, by, bz);
    const int tid = threadIdx.x;
    const int lane = tid & 63, wv = tid >> 6;
    const int wm = wv >> 1, wn = wv & 1;
    const int row0 = bx * BM, col0 = by * BN;

    const unsigned short* Ab = A + (size_t)bz * sA + (size_t)row0 * K;
    const unsigned short* Bb = Bt + (size_t)bz * sB + (size_t)col0 * K;

    f32x4 acc[FM][FN] = {};
    gemm_core<BM, BN, true>(Ab, Bb, K, lsA, lsB, acc, lane, wv);

    const int lr4 = (lane >> 4) * 4;
    const int lc = lane & 15;
#pragma unroll
    for (int fi = 0; fi < FM; ++fi) {
        int r = row0 + wm * (BM / 2) + fi * 16 + lc;
#pragma unroll
        for (int fj = 0; fj < FN; ++fj) {
            int cb = col0 + wn * (BN / 2) + fj * 16 + lr4;
            f32x4 v = acc[fi][fj];
            if constexpr (EPI == 3) {   // relu^2 + key mask (cols = keys t)
                unsigned short* C = (unsigned short*)Cp + (size_t)bz * sC;
                int flag = *flagp;
                ushort4 ov;
#pragma unroll
                for (int g = 0; g < 4; ++g) {
                    int c = cb + g;
                    int mv = flag ? (int)((const unsigned char*)aux)[bz * sAux + c]
                                  : ((const int*)aux)[bz * sAux + c];
                    float vv = fmaxf(v[g], 0.0f);
                    vv *= vv;
                    ((unsigned short*)&ov)[g] = mv ? (unsigned short)0 : f2bf(vv);
                }
                *(ushort4*)&C[(size_t)r * N + cb] = ov;
            } else if constexpr (EPI == 4) {   // o = u * (a@v)
                const unsigned short* U = (const unsigned short*)aux + (size_t)bz * sAux;
                unsigned short* C = (unsigned short*)Cp + (size_t)bz * sC;
                size_t off = (size_t)r * N + cb;
                ushort4 uu = *(const ushort4*)&U[off];
                ushort4 ov = {f2bf(bf2f(uu.x) * v[0]), f2bf(bf2f(uu.y) * v[1]),
                              f2bf(bf2f(uu.z) * v[2]), f2bf(bf2f(uu.w) * v[3])};
                *(ushort4*)&C[off] = ov;
            } else {                           // EPI 5: bias + residual, f32 in-place
                float* C = (float*)Cp;
                const float* X = (const float*)aux;
                size_t off = (size_t)r * N + cb;
                f32x4 bb = *(const f32x4*)&bias[cb];
                f32x4 xx = *(const f32x4*)&X[off];
                f32x4 ov = {v[0] + bb[0] + xx[0], v[1] + bb[1] + xx[1],
                            v[2] + bb[2] + xx[2], v[3] + bb[3] + xx[3]};
                *(f32x4*)&C[off] = ov;
            }
        }
    }
}

extern "C" void kernel_launch(void* const* d_in, const int* in_sizes, int n_in,
                              void* d_out, int out_size, void* d_ws, size_t ws_size,
                              hipStream_t stream) {
    const int* tok = (const int*)d_in[0];
    const unsigned char* mask = (const unsigned char*)d_in[1];
    const float* embed = (const float*)d_in[2];
    const float* ln_g = (const float*)d_in[3];
    const float* ln_b = (const float*)d_in[4];
    const float* Wz = (const float*)d_in[5];
    const float* bz = (const float*)d_in[6];
    const float* gq = (const float*)d_in[7];
    const float* bq = (const float*)d_in[8];
    const float* gk = (const float*)d_in[9];
    const float* bk = (const float*)d_in[10];
    const float* Wu = (const float*)d_in[11];
    const float* bu = (const float*)d_in[12];
    const float* Wv = (const float*)d_in[13];
    const float* bv = (const float*)d_in[14];
    const float* Wo = (const float*)d_in[15];
    const float* bo = (const float*)d_in[16];
    const float* fin_g = (const float*)d_in[17];
    const float* fin_b = (const float*)d_in[18];

    char* wsb = (char*)d_ws;
    size_t off = 0;
    auto alloc = [&](size_t nbytes) {
        void* p = wsb + off;
        off = (off + nbytes + 255) & ~(size_t)255;
        return p;
    };
    int* flag = (int*)alloc(256);
    float* x = (float*)alloc((size_t)B * S * D * 4);
    unsigned short* xn = (unsigned short*)alloc((size_t)B * S * D * 2);
    unsigned short* q = (unsigned short*)alloc((size_t)B * S * SD * 2);
    unsigned short* k = (unsigned short*)alloc((size_t)B * S * SD * 2);
    unsigned short* u = (unsigned short*)alloc((size_t)B * S * E * 2);
    unsigned short* vt = (unsigned short*)alloc((size_t)B * E * S * 2);
    unsigned short* o = (unsigned short*)alloc((size_t)B * S * E * 2);
    unsigned short* a = (unsigned short*)alloc((size_t)B * S * S * 2);
    unsigned short* Wuvzt = (unsigned short*)alloc((size_t)L * 3200 * D * 2);
    unsigned short* Wot = (unsigned short*)alloc((size_t)L * D * E * 2);

    constexpr long WUVZ = 3200L * D;   // per-layer stride of concat weight [u|v|z]

    detect_mask_kernel<<<1, 256, 0, stream>>>(mask, flag);
    embed_kernel<<<(B * S * D) / 256, 256, 0, stream>>>(tok, embed, x);
    tcast_kernel<<<dim3(D / 32, E / 32, L), dim3(32, 8), 0, stream>>>(Wu, Wuvzt, D, E, WUVZ);
    tcast_kernel<<<dim3(D / 32, E / 32, L), dim3(32, 8), 0, stream>>>(
        Wv, Wuvzt + 1536L * D, D, E, WUVZ);
    tcast_kernel<<<dim3(D / 32, SD / 32, L), dim3(32, 8), 0, stream>>>(
        Wz, Wuvzt + 3072L * D, D, SD, WUVZ);
    tcast_kernel<<<dim3(E / 32, D / 32, L), dim3(32, 8), 0, stream>>>(
        Wo, Wot, E, D, (long)D * E);

    for (int l = 0; l < L; ++l) {
        ln_kernel<true><<<B * S / 4, 256, 0, stream>>>(x, ln_g + l * D, ln_b + l * D, xn);
        uv_gemm<<<dim3(64, 12, 2), 256, 0, stream>>>(
            xn, Wuvzt + (size_t)l * WUVZ, bu + l * E, bv + l * E, u, vt);
        zqk_gemm<<<dim3(64, 1), 256, 0, stream>>>(
            xn, Wuvzt + (size_t)l * WUVZ + 3072L * D, bz + l * SD,
            gq + (size_t)l * S * SD, bq + (size_t)l * S * SD,
            gk + (size_t)l * S * SD, bk + (size_t)l * S * SD, q, k);
        mgemm<3, 64, 64><<<dim3(8, 8, B), 256, 0, stream>>>(
            q, k, nullptr, mask, flag, a, S, SD,
            (long)S * SD, (long)S * SD, (long)S * S, S);
        mgemm<4, 128, 128><<<dim3(4, 12, B), 256, 0, stream>>>(
            a, vt, nullptr, u, nullptr, o, E, S,
            (long)S * S, (long)E * S, (long)S * E, (long)S * E);
        mgemm<5, 128, 64><<<dim3(64, 8), 256, 0, stream>>>(
            o, Wot + (size_t)l * D * E, bo + l * D, x, nullptr, x, D, E, 0, 0, 0, 0);
    }
    ln_kernel<false><<<B * S / 4, 256, 0, stream>>>(x, fin_g, fin_b, (float*)d_out);
}